// Round 7
// baseline (693.675 us; speedup 1.0000x reference)
//
#include <hip/hip_runtime.h>

#define NV 20000          // vertices
#define NE 4096           // hyperedges
#define FT 128            // features
#define NW_E 128          // u32 words per packed vertex row  (E/32)
#define NW_V 625          // real u32 words per packedT edge row (N/32)
#define PT_STRIDE 632     // padded packedT row stride (prefetch may read past word 625)
#define NKC 313           // padded n-chunks of 64 (313*64 = 20032)

typedef __attribute__((ext_vector_type(8))) short short8v;   // 8 bf16 — MFMA A/B frag
typedef __attribute__((ext_vector_type(4))) float float4v;   // 4 fp32 — MFMA C/D frag

__device__ __forceinline__ unsigned short f2bf(float f) {    // fp32 -> bf16 RNE
    unsigned u = __float_as_uint(f);
    u += 0x7FFFu + ((u >> 16) & 1u);
    return (unsigned short)(u >> 16);
}
// swizzled LDS tile: rows of 64 bf16 (128B), 16B chunks XORed by row
__device__ __forceinline__ int lds_off(int r, int chunk) {
    return r * 128 + ((chunk ^ (r & 7)) << 4);
}
// 8 H-bits -> 8 bf16 {0.0,1.0} in VGPRs (no LDS, no LUT)
__device__ __forceinline__ short8v expand8(unsigned b) {
    union { unsigned u[4]; short8v s; } r;
#pragma unroll
    for (int j = 0; j < 4; ++j) {
        unsigned lo = 0u - (b & 1u);
        unsigned hi = 0u - (b & 2u);
        r.u[j] = (lo & 0x3F80u) | (hi & 0x3F800000u);
        b >>= 2;
    }
    return r.s;
}

// ---------------- 1. pack H -> bits, coalesced: wave = half row ----------------
__global__ __launch_bounds__(256) void k_pack(const int* __restrict__ H,
                                              unsigned* __restrict__ packed,
                                              float* __restrict__ dv) {
    __shared__ int cl[4];
    int t = threadIdx.x, wave = t >> 6, lane = t & 63;
    int row = blockIdx.x * 2 + (wave >> 1);
    int half = wave & 1;
    const uint4* base = reinterpret_cast<const uint4*>(H) + (size_t)row * 1024 + half * 512 + lane * 8;
    unsigned m = 0;
#pragma unroll
    for (int i = 0; i < 8; ++i) {
        uint4 v = base[i];
        m |= (v.x ? 1u : 0u) << (i * 4 + 0);
        m |= (v.y ? 1u : 0u) << (i * 4 + 1);
        m |= (v.z ? 1u : 0u) << (i * 4 + 2);
        m |= (v.w ? 1u : 0u) << (i * 4 + 3);
    }
    packed[(size_t)row * NW_E + half * 64 + lane] = m;
    int c = __popc(m);
    for (int o = 32; o > 0; o >>= 1) c += __shfl_down(c, o, 64);
    if (lane == 0) cl[wave] = c;
    __syncthreads();
    if (t < 2) {
        int d = cl[t * 2] + cl[t * 2 + 1];
        dv[blockIdx.x * 2 + t] = d > 0 ? 1.0f / sqrtf((float)d) : 1.0f;
    }
}

// ---------------- 2. bit-transpose packed -> packedT + edge-degree atomics ----------------
__global__ __launch_bounds__(256) void k_btrans(const unsigned* __restrict__ packed,
                                                unsigned* __restrict__ packedT,
                                                int* __restrict__ edeg) {
    int lane = threadIdx.x & 63;
    int w = threadIdx.x >> 6;
    int ew = blockIdx.y * 4 + w;
    int n = blockIdx.x * 64 + lane;
    unsigned wv = (n < NV) ? packed[(size_t)n * NW_E + ew] : 0u;
    unsigned my = 0;
#pragma unroll
    for (int j = 0; j < 32; ++j) {
        unsigned long long m = __ballot(((wv >> j) & 1u) != 0);
        unsigned part = (lane < 32) ? (unsigned)m : (unsigned)(m >> 32);
        if ((lane & 31) == j) my = part;
    }
    int nw = blockIdx.x * 2 + (lane >> 5);
    int e = ew * 32 + (lane & 31);
    if (nw <= 625) {
        packedT[(size_t)e * PT_STRIDE + nw] = my;
        if (my) atomicAdd(&edeg[e], __popc(my));
    }
}

// ---------------- 3. At[kc][f][64n] = bf16(dv*X), tiled for mm1 A staging ----------------
__global__ __launch_bounds__(256) void k_mid(const float* __restrict__ X,
                                             const float* __restrict__ dv,
                                             unsigned short* __restrict__ At) {
    int b = blockIdx.x, t = threadIdx.x;
    if (b < 1250) {
        int f = t & 127;
        int nb = (b * 2 + (t >> 7)) * 8;   // 1250 * 16 n == 20000 exactly
        unsigned short h[8];
#pragma unroll
        for (int i = 0; i < 8; ++i) {
            int n = nb + i;
            h[i] = f2bf(X[(size_t)n * FT + f] * dv[n]);
        }
        uint4 u;
        u.x = (unsigned)h[0] | ((unsigned)h[1] << 16);
        u.y = (unsigned)h[2] | ((unsigned)h[3] << 16);
        u.z = (unsigned)h[4] | ((unsigned)h[5] << 16);
        u.w = (unsigned)h[6] | ((unsigned)h[7] << 16);
        int kc = nb >> 6;
        *reinterpret_cast<uint4*>(At + (size_t)kc * 8192 + f * 64 + (nb & 63)) = u;
    } else {
        // zero pad chunk kc=312, j in [32,64)
        int f = t & 127;
        uint4 z = {0, 0, 0, 0};
        *reinterpret_cast<uint4*>(At + (size_t)312 * 8192 + f * 64 + 32 + (t >> 7) * 8) = z;
        *reinterpret_cast<uint4*>(At + (size_t)312 * 8192 + f * 64 + 48 + (t >> 7) * 8) = z;
    }
}

// ---------------- 4. mm1: P[kp][f][e] = sum_n At[f][n] * H[n][e], split-K ----------------
// A staged bf16 (manual, coalesced); B staged as RAW BITS (1KB), frags expanded in VGPRs.
__global__ __launch_bounds__(256, 2) void k_mm1(const unsigned short* __restrict__ At,
                                                const unsigned* __restrict__ packedT,
                                                float* __restrict__ P, int chunkK) {
    __shared__ __align__(16) unsigned char sA[16384];     // swizzled 128 f x 64 n bf16
    __shared__ __align__(8) unsigned char sBbits[1024];   // 128 e-rows x 8 B of H^T bits
    int t = threadIdx.x;

    int et = blockIdx.x & 31, kp = blockIdx.x >> 5;
    int e0 = et * 128;
    int kbeg = kp * chunkK;
    int kend = kbeg + chunkK; if (kend > NKC * 64) kend = NKC * 64;
    int iters = (kend - kbeg) >> 6; if (iters < 0) iters = 0;

    float4v acc[4][4];
#pragma unroll
    for (int i = 0; i < 4; ++i)
#pragma unroll
        for (int j = 0; j < 4; ++j)
#pragma unroll
            for (int r = 0; r < 4; ++r) acc[i][j][r] = 0.0f;

    int wave = t >> 6, lane = t & 63;
    int wm0 = (wave & 1) * 64, wc0 = (wave >> 1) * 64;
    int r0 = lane & 15, q = lane >> 4, qs = q * 8;

    // B bit prefetch: thread t<128 owns e-row t; uint4 = 4 words = 2 iters
    const unsigned* brow = packedT + (size_t)(e0 + (t & 127)) * PT_STRIDE + (kbeg >> 5);
    uint4 bw, bw2;
    if (t < 128) bw = *reinterpret_cast<const uint4*>(brow);

    for (int it = 0; it < iters; ++it) {
        int kc = (kbeg >> 6) + it;
        // stage A: 16KB bf16, 256 thr x 4 x 16B coalesced
        const uint4* slab = reinterpret_cast<const uint4*>(At + (size_t)kc * 8192);
#pragma unroll
        for (int c = 0; c < 4; ++c) {
            int idx = c * 256 + t;
            uint4 v = slab[idx];
            *reinterpret_cast<uint4*>(sA + lds_off(idx >> 3, idx & 7)) = v;
        }
        // stage B bits: 8 B per e-row
        if (t < 128) {
            uint2 wpair;
            if (!(it & 1)) {
                bw2 = *reinterpret_cast<const uint4*>(brow + 2 * it + 4);  // pad keeps in-bounds
                wpair.x = bw.x; wpair.y = bw.y;
            } else {
                wpair.x = bw.z; wpair.y = bw.w;
                bw = bw2;
            }
            *reinterpret_cast<uint2*>(sBbits + t * 8) = wpair;
        }
        __syncthreads();
        // read bit rows for this wave's 4 e-frag groups (conflict-free b64)
        uint2 bv[4];
#pragma unroll
        for (int ci = 0; ci < 4; ++ci)
            bv[ci] = *reinterpret_cast<const uint2*>(sBbits + (wc0 + ci * 16 + r0) * 8);
#pragma unroll
        for (int ks = 0; ks < 2; ++ks) {
            short8v a[4];
#pragma unroll
            for (int mi = 0; mi < 4; ++mi)
                a[mi] = *reinterpret_cast<const short8v*>(sA + lds_off(wm0 + mi * 16 + r0, ks * 4 + q));
#pragma unroll
            for (int ci = 0; ci < 4; ++ci) {
                unsigned byte = ((ks ? bv[ci].y : bv[ci].x) >> qs) & 0xFFu;
                short8v bb = expand8(byte);
#pragma unroll
                for (int mi = 0; mi < 4; ++mi)
                    acc[mi][ci] = __builtin_amdgcn_mfma_f32_16x16x32_bf16(a[mi], bb, acc[mi][ci], 0, 0, 0);
            }
        }
        __syncthreads();
    }
    float* Pp = P + (size_t)kp * (128 * 4096);
#pragma unroll
    for (int mi = 0; mi < 4; ++mi)
#pragma unroll
        for (int ci = 0; ci < 4; ++ci) {
            int f = wm0 + mi * 16 + q * 4;
            int e = e0 + wc0 + ci * 16 + r0;
#pragma unroll
            for (int r = 0; r < 4; ++r)
                Pp[(size_t)(f + r) * 4096 + e] = acc[mi][ci][r];
        }
}

// ---------------- 5. reduce split-K partials ----------------
__global__ __launch_bounds__(256) void k_reduce(const float4v* __restrict__ P,
                                                float4v* __restrict__ Tt, int S) {
    int i = blockIdx.x * 256 + threadIdx.x;   // 131072 float4 total
    float4v a = P[i];
    for (int p = 1; p < S; ++p) a += P[(size_t)p * 131072 + i];
    Tt[i] = a;
}

// ---------------- 6. Ut[ec][g][64e] = bf16( de * (Tt^T W)^T ), tiled for mm2 ----------------
__global__ __launch_bounds__(256) void k_ut(const float* __restrict__ Tt,
                                            const float* __restrict__ W,
                                            const int* __restrict__ edeg,
                                            unsigned short* __restrict__ Ut) {
    int t = threadIdx.x;
    int bx = blockIdx.x;
    int e = bx * 64 + (t & 63);
    int g0 = blockIdx.y * 16 + (t >> 6) * 4;
    float a0 = 0, a1 = 0, a2 = 0, a3 = 0;
    for (int f = 0; f < 128; ++f) {
        float tv = Tt[(size_t)f * 4096 + e];
        float4 wv = *reinterpret_cast<const float4*>(W + f * 128 + g0);
        a0 += tv * wv.x; a1 += tv * wv.y; a2 += tv * wv.z; a3 += tv * wv.w;
    }
    int dgi = edeg[e];
    float d = dgi > 0 ? 1.0f / (float)dgi : 1.0f;
    int j = t & 63;
    Ut[(size_t)bx * 8192 + (g0 + 0) * 64 + j] = f2bf(a0 * d);
    Ut[(size_t)bx * 8192 + (g0 + 1) * 64 + j] = f2bf(a1 * d);
    Ut[(size_t)bx * 8192 + (g0 + 2) * 64 + j] = f2bf(a2 * d);
    Ut[(size_t)bx * 8192 + (g0 + 3) * 64 + j] = f2bf(a3 * d);
}

// ---------------- 7. mm2: out[n][g] = dv[n]*sum_e H[n][e]*U[g][e] + bias[g] ----------------
// A staged as RAW BITS (1KB, frags expanded in VGPRs); B staged bf16 from tiled Ut.
__global__ __launch_bounds__(256, 4) void k_mm2(const unsigned* __restrict__ packed,
                                                const unsigned short* __restrict__ Ut,
                                                const float* __restrict__ dv,
                                                const float* __restrict__ bias,
                                                float* __restrict__ out) {
    __shared__ __align__(8) unsigned char sAbits[1024];   // 128 n-rows x 8 B of H bits
    __shared__ __align__(16) unsigned char sB[4096];      // swizzled 32 g x 64 e bf16
    int t = threadIdx.x;

    int mt = blockIdx.x >> 2, qg = blockIdx.x & 3;
    int n0 = mt * 128, g0 = qg * 32;

    float4v acc[4];
#pragma unroll
    for (int i = 0; i < 4; ++i)
#pragma unroll
        for (int r = 0; r < 4; ++r) acc[i][r] = 0.0f;

    int wave = t >> 6, lane = t & 63;
    int wm0 = (wave & 1) * 64, wc0 = (wave >> 1) * 16;
    int r0 = lane & 15, q = lane >> 4, qs = q * 8;

    const unsigned* arow = packed + (size_t)(n0 + (t & 127)) * NW_E;
    const unsigned short* bbase = Ut + (size_t)qg * 2048;
    int t2 = t - 128;
    uint4 aw, aw2;
    if (t < 128) aw = *reinterpret_cast<const uint4*>(arow);

    for (int it = 0; it < 64; ++it) {
        if (t < 128) {
            // stage A bits: 8 B per n-row
            uint2 wpair;
            if (!(it & 1)) {
                aw2 = *reinterpret_cast<const uint4*>(arow + 2 * it + 4);  // over-read benign
                wpair.x = aw.x; wpair.y = aw.y;
            } else {
                wpair.x = aw.z; wpair.y = aw.w;
                aw = aw2;
            }
            *reinterpret_cast<uint2*>(sAbits + t * 8) = wpair;
        } else {
            // stage B: 4KB contiguous (32 g-rows x 64 e), 128 thr x 2 x 16B
            const uint4* src = reinterpret_cast<const uint4*>(bbase + (size_t)it * 8192);
#pragma unroll
            for (int c = 0; c < 2; ++c) {
                int idx = t2 * 2 + c;
                uint4 v = src[idx];
                *reinterpret_cast<uint4*>(sB + lds_off(idx >> 3, idx & 7)) = v;
            }
        }
        __syncthreads();
        uint2 av[4];
#pragma unroll
        for (int mi = 0; mi < 4; ++mi)
            av[mi] = *reinterpret_cast<const uint2*>(sAbits + (wm0 + mi * 16 + r0) * 8);
#pragma unroll
        for (int ks = 0; ks < 2; ++ks) {
            short8v bb = *reinterpret_cast<const short8v*>(sB + lds_off(wc0 + r0, ks * 4 + q));
#pragma unroll
            for (int mi = 0; mi < 4; ++mi) {
                unsigned byte = ((ks ? av[mi].y : av[mi].x) >> qs) & 0xFFu;
                short8v a = expand8(byte);
                acc[mi] = __builtin_amdgcn_mfma_f32_16x16x32_bf16(a, bb, acc[mi], 0, 0, 0);
            }
        }
        __syncthreads();
    }
    {
        int g = g0 + wc0 + r0;
        float bg = bias[g];
#pragma unroll
        for (int mi = 0; mi < 4; ++mi) {
#pragma unroll
            for (int r = 0; r < 4; ++r) {
                int n = n0 + wm0 + mi * 16 + q * 4 + r;
                if (n < NV) out[(size_t)n * 128 + g] = dv[n] * acc[mi][r] + bg;
            }
        }
    }
}

extern "C" void kernel_launch(void* const* d_in, const int* in_sizes, int n_in,
                              void* d_out, int out_size, void* d_ws, size_t ws_size,
                              hipStream_t stream) {
    const float* X    = (const float*)d_in[0];
    const int*   H    = (const int*)d_in[1];
    const float* W    = (const float*)d_in[2];
    const float* bias = (const float*)d_in[3];
    float* out = (float*)d_out;

    char* ws = (char*)d_ws;
    size_t off = 0;
    auto alloc = [&](size_t sz) { char* p = ws + off; off += (sz + 255) & ~(size_t)255; return p; };
    unsigned*       packed  = (unsigned*)alloc((size_t)NV * NW_E * 4);          // 10.24 MB
    unsigned*       packedT = (unsigned*)alloc((size_t)NE * PT_STRIDE * 4);     // 10.35 MB
    unsigned short* At      = (unsigned short*)alloc((size_t)NKC * 8192 * 2);   //  5.13 MB
    float*          Tt      = (float*)alloc((size_t)FT * NE * 4);               //  2.10 MB
    unsigned short* Ut      = (unsigned short*)alloc((size_t)FT * NE * 2);      //  1.05 MB
    float*          dv      = (float*)alloc((size_t)NV * 4);
    int*            edeg    = (int*)alloc((size_t)NE * 4);
    size_t fixed = off;

    long long avail = (long long)ws_size - (long long)fixed;
    int S = (int)(avail / (128LL * 4096 * 4));
    if (S > 16) S = 16;
    if (S < 1) S = 1;
    float* P1 = (float*)(ws + fixed);
    int chunkK = ((NKC * 64 + S * 64 - 1) / (S * 64)) * 64;

    hipMemsetAsync(edeg, 0, (size_t)NE * 4, stream);
    k_pack  <<<NV / 2, 256, 0, stream>>>(H, packed, dv);
    k_btrans<<<dim3(313, 32), 256, 0, stream>>>(packed, packedT, edeg);
    k_mid   <<<1251, 256, 0, stream>>>(X, dv, At);
    k_mm1   <<<32 * S, 256, 0, stream>>>(At, packedT, P1, chunkK);
    k_reduce<<<512, 256, 0, stream>>>((const float4v*)P1, (float4v*)Tt, S);
    k_ut    <<<dim3(64, 8), 256, 0, stream>>>(Tt, W, edeg, Ut);
    k_mm2   <<<628, 256, 0, stream>>>(packed, Ut, dv, bias, out);
}

// Round 8
// 666.175 us; speedup vs baseline: 1.0413x; 1.0413x over previous
//
#include <hip/hip_runtime.h>

#define NV 20000          // vertices
#define NE 4096           // hyperedges
#define FT 128            // features
#define NW_E 128          // u32 words per packed vertex row  (E/32)
#define NW_V 625          // real u32 words per packedT edge row (N/32)
#define PT_STRIDE 632     // padded packedT row stride (prefetch may read past word 625)
#define NKC 313           // padded n-chunks of 64 (313*64 = 20032)

typedef __attribute__((ext_vector_type(8))) short short8v;   // 8 bf16 — MFMA A/B frag
typedef __attribute__((ext_vector_type(4))) float float4v;   // 4 fp32 — MFMA C/D frag

__device__ __forceinline__ unsigned short f2bf(float f) {    // fp32 -> bf16 RNE
    unsigned u = __float_as_uint(f);
    u += 0x7FFFu + ((u >> 16) & 1u);
    return (unsigned short)(u >> 16);
}
// swizzled LDS tile: rows of 64 bf16 (128B), 16B chunks XORed by row
__device__ __forceinline__ int lds_off(int r, int chunk) {
    return r * 128 + ((chunk ^ (r & 7)) << 4);
}
// 16B LUT entry: byte -> 8 bf16 in {0.0, 1.0}
__device__ __forceinline__ uint4 lut_entry(int t) {
    uint4 e;
    e.x = ((t & 1) ? 0x3F80u : 0u) | ((t & 2) ? 0x3F800000u : 0u);
    e.y = ((t & 4) ? 0x3F80u : 0u) | ((t & 8) ? 0x3F800000u : 0u);
    e.z = ((t & 16) ? 0x3F80u : 0u) | ((t & 32) ? 0x3F800000u : 0u);
    e.w = ((t & 64) ? 0x3F80u : 0u) | ((t & 128) ? 0x3F800000u : 0u);
    return e;
}

// ---------------- 1. pack H -> bits, coalesced: wave = half row ----------------
__global__ __launch_bounds__(256) void k_pack(const int* __restrict__ H,
                                              unsigned* __restrict__ packed,
                                              float* __restrict__ dv) {
    __shared__ int cl[4];
    int t = threadIdx.x, wave = t >> 6, lane = t & 63;
    int row = blockIdx.x * 2 + (wave >> 1);
    int half = wave & 1;
    const uint4* base = reinterpret_cast<const uint4*>(H) + (size_t)row * 1024 + half * 512 + lane * 8;
    unsigned m = 0;
#pragma unroll
    for (int i = 0; i < 8; ++i) {
        uint4 v = base[i];
        m |= (v.x ? 1u : 0u) << (i * 4 + 0);
        m |= (v.y ? 1u : 0u) << (i * 4 + 1);
        m |= (v.z ? 1u : 0u) << (i * 4 + 2);
        m |= (v.w ? 1u : 0u) << (i * 4 + 3);
    }
    packed[(size_t)row * NW_E + half * 64 + lane] = m;
    int c = __popc(m);
    for (int o = 32; o > 0; o >>= 1) c += __shfl_down(c, o, 64);
    if (lane == 0) cl[wave] = c;
    __syncthreads();
    if (t < 2) {
        int d = cl[t * 2] + cl[t * 2 + 1];
        dv[blockIdx.x * 2 + t] = d > 0 ? 1.0f / sqrtf((float)d) : 1.0f;
    }
}

// ---------------- 2. merged prep: bit-transpose + edge-degree | At tiled build ----------------
// blocks [0,10016): ballot transpose of packed -> packedT, edeg atomics
// blocks [10016,11266): At[kc][f][64n] = bf16(dv*X); block 11266: zero-pad kc=312 tail
__global__ __launch_bounds__(256) void k_prep(const unsigned* __restrict__ packed,
                                              const float* __restrict__ X,
                                              const float* __restrict__ dv,
                                              unsigned* __restrict__ packedT,
                                              int* __restrict__ edeg,
                                              unsigned short* __restrict__ At) {
    int v = blockIdx.x, t = threadIdx.x;
    if (v < 10016) {
        int bx = v % 313, by = v / 313;
        int lane = t & 63;
        int w = t >> 6;
        int ew = by * 4 + w;
        int n = bx * 64 + lane;
        unsigned wv = (n < NV) ? packed[(size_t)n * NW_E + ew] : 0u;
        unsigned my = 0;
#pragma unroll
        for (int j = 0; j < 32; ++j) {
            unsigned long long m = __ballot(((wv >> j) & 1u) != 0);
            unsigned part = (lane < 32) ? (unsigned)m : (unsigned)(m >> 32);
            if ((lane & 31) == j) my = part;
        }
        int nw = bx * 2 + (lane >> 5);
        int e = ew * 32 + (lane & 31);
        if (nw <= 625) {
            packedT[(size_t)e * PT_STRIDE + nw] = my;
            if (my) atomicAdd(&edeg[e], __popc(my));
        }
    } else {
        int b = v - 10016;
        if (b < 1250) {
            int f = t & 127;
            int nb = (b * 2 + (t >> 7)) * 8;   // 1250 * 16 n == 20000 exactly
            unsigned short h[8];
#pragma unroll
            for (int i = 0; i < 8; ++i) {
                int n = nb + i;
                h[i] = f2bf(X[(size_t)n * FT + f] * dv[n]);
            }
            uint4 u;
            u.x = (unsigned)h[0] | ((unsigned)h[1] << 16);
            u.y = (unsigned)h[2] | ((unsigned)h[3] << 16);
            u.z = (unsigned)h[4] | ((unsigned)h[5] << 16);
            u.w = (unsigned)h[6] | ((unsigned)h[7] << 16);
            int kc = nb >> 6;
            *reinterpret_cast<uint4*>(At + (size_t)kc * 8192 + f * 64 + (nb & 63)) = u;
        } else {
            // zero pad chunk kc=312, n = 20000..20031
            int f = t & 127;
            uint4 z = {0, 0, 0, 0};
            *reinterpret_cast<uint4*>(At + (size_t)312 * 8192 + f * 64 + 32 + (t >> 7) * 8) = z;
            *reinterpret_cast<uint4*>(At + (size_t)312 * 8192 + f * 64 + 48 + (t >> 7) * 8) = z;
        }
    }
}

// ---------------- 3. mm1: P[kp][f][e] = sum_n At[f][n] * H[n][e], split-K ----------------
// R5-exact: A staged bf16 coalesced; B bits -> LUT expansion at staging time.
__global__ __launch_bounds__(256, 2) void k_mm1(const unsigned short* __restrict__ At,
                                                const unsigned* __restrict__ packedT,
                                                float* __restrict__ P, int chunkK) {
    __shared__ __align__(16) unsigned char sA[16384];   // swizzled 128 f x 64 n bf16
    __shared__ __align__(16) unsigned char sB[16384];   // swizzled 128 e x 64 n bf16
    __shared__ __align__(16) uint4 slut[256];
    int t = threadIdx.x;
    slut[t] = lut_entry(t);

    int et = blockIdx.x & 31, kp = blockIdx.x >> 5;
    int e0 = et * 128;
    int kbeg = kp * chunkK;
    int kend = kbeg + chunkK; if (kend > NKC * 64) kend = NKC * 64;
    int iters = (kend - kbeg) >> 6; if (iters < 0) iters = 0;

    float4v acc[4][4];
#pragma unroll
    for (int i = 0; i < 4; ++i)
#pragma unroll
        for (int j = 0; j < 4; ++j)
#pragma unroll
            for (int r = 0; r < 4; ++r) acc[i][j][r] = 0.0f;

    int wave = t >> 6, lane = t & 63;
    int wm0 = (wave & 1) * 64, wc0 = (wave >> 1) * 64;
    int r0 = lane & 15, q = lane >> 4;

    // B prefetch: thread t<128 owns e-row t; uint4 = 4 words = 2 iters
    const unsigned* brow = packedT + (size_t)(e0 + (t & 127)) * PT_STRIDE + (kbeg >> 5);
    uint4 bw, bw2;
    if (t < 128) bw = *reinterpret_cast<const uint4*>(brow);
    __syncthreads();   // LUT ready

    for (int it = 0; it < iters; ++it) {
        int kc = (kbeg >> 6) + it;
        // stage A: 16KB contiguous slab, 256 thr x 4 x 16B, per-instr coalesced
        const uint4* slab = reinterpret_cast<const uint4*>(At + (size_t)kc * 8192);
#pragma unroll
        for (int c = 0; c < 4; ++c) {
            int idx = c * 256 + t;
            uint4 v = slab[idx];
            *reinterpret_cast<uint4*>(sA + lds_off(idx >> 3, idx & 7)) = v;
        }
        // stage B: 2 words/row via LUT; prefetch next pair at even iters
        if (t < 128) {
            unsigned w0, w1;
            if (!(it & 1)) {
                bw2 = *reinterpret_cast<const uint4*>(brow + 2 * it + 4);  // pad keeps in-bounds
                w0 = bw.x; w1 = bw.y;
            } else {
                w0 = bw.z; w1 = bw.w;
            }
            int rB = t;
#pragma unroll
            for (int c = 0; c < 4; ++c)
                *reinterpret_cast<uint4*>(sB + lds_off(rB, c)) = slut[(w0 >> (c * 8)) & 0xFF];
#pragma unroll
            for (int c = 0; c < 4; ++c)
                *reinterpret_cast<uint4*>(sB + lds_off(rB, 4 + c)) = slut[(w1 >> (c * 8)) & 0xFF];
            if (it & 1) bw = bw2;
        }
        __syncthreads();
#pragma unroll
        for (int ks = 0; ks < 2; ++ks) {
            short8v a[4], bb[4];
#pragma unroll
            for (int mi = 0; mi < 4; ++mi)
                a[mi] = *reinterpret_cast<const short8v*>(sA + lds_off(wm0 + mi * 16 + r0, ks * 4 + q));
#pragma unroll
            for (int ci = 0; ci < 4; ++ci)
                bb[ci] = *reinterpret_cast<const short8v*>(sB + lds_off(wc0 + ci * 16 + r0, ks * 4 + q));
#pragma unroll
            for (int mi = 0; mi < 4; ++mi)
#pragma unroll
                for (int ci = 0; ci < 4; ++ci)
                    acc[mi][ci] = __builtin_amdgcn_mfma_f32_16x16x32_bf16(a[mi], bb[ci], acc[mi][ci], 0, 0, 0);
        }
        __syncthreads();
    }
    float* Pp = P + (size_t)kp * (128 * 4096);
#pragma unroll
    for (int mi = 0; mi < 4; ++mi)
#pragma unroll
        for (int ci = 0; ci < 4; ++ci) {
            int f = wm0 + mi * 16 + q * 4;
            int e = e0 + wc0 + ci * 16 + r0;
#pragma unroll
            for (int r = 0; r < 4; ++r)
                Pp[(size_t)(f + r) * 4096 + e] = acc[mi][ci][r];
        }
}

// ---------------- 4. fused reduce + Ut: Ut[ec][g][64e] = bf16( de * (sum_p P)^T W ) ----------------
// 128 blocks x 32 e. Phase A: sum S partials into 16KB LDS tile. Phase B: fp32 epilogue GEMM.
__global__ __launch_bounds__(256) void k_ut2(const float* __restrict__ P,
                                             const float* __restrict__ W,
                                             const int* __restrict__ edeg,
                                             unsigned short* __restrict__ Ut, int S) {
    __shared__ float sT[128][32];   // 16 KB, [f][e-local]
    int t = threadIdx.x;
    int e0 = blockIdx.x * 32;
    int el = t & 31;
    int fb = t >> 5;                // 0..7
    float a[16];
#pragma unroll
    for (int i = 0; i < 16; ++i) a[i] = 0.0f;
    for (int p = 0; p < S; ++p) {
        const float* Pp = P + (size_t)p * 524288 + e0 + el;
#pragma unroll
        for (int i = 0; i < 16; ++i)
            a[i] += Pp[(size_t)(fb + i * 8) * 4096];
    }
#pragma unroll
    for (int i = 0; i < 16; ++i) sT[fb + i * 8][el] = a[i];
    __syncthreads();
    // phase B: thread = (el, gq = t>>5): 16 g outputs
    int g0 = (t >> 5) * 16;
    float acc[16];
#pragma unroll
    for (int j = 0; j < 16; ++j) acc[j] = 0.0f;
    for (int f = 0; f < 128; ++f) {
        float tv = sT[f][el];
#pragma unroll
        for (int j = 0; j < 4; ++j) {
            float4 wv = *reinterpret_cast<const float4*>(W + f * 128 + g0 + j * 4);
            acc[j * 4 + 0] += tv * wv.x;
            acc[j * 4 + 1] += tv * wv.y;
            acc[j * 4 + 2] += tv * wv.z;
            acc[j * 4 + 3] += tv * wv.w;
        }
    }
    int e = e0 + el;
    int dgi = edeg[e];
    float d = dgi > 0 ? 1.0f / (float)dgi : 1.0f;
    size_t base = (size_t)(e >> 6) * 8192 + (e & 63);
#pragma unroll
    for (int j = 0; j < 16; ++j)
        Ut[base + (size_t)(g0 + j) * 64] = f2bf(acc[j] * d);
}

// ---------------- 5. mm2: out[n][g] = dv[n]*sum_e H[n][e]*U[g][e] + bias[g] ----------------
// R5-exact: A bits -> LUT at staging (t<128, uint4 prefetch); B bf16 from tiled Ut (t>=128).
__global__ __launch_bounds__(256, 4) void k_mm2(const unsigned* __restrict__ packed,
                                                const unsigned short* __restrict__ Ut,
                                                const float* __restrict__ dv,
                                                const float* __restrict__ bias,
                                                float* __restrict__ out) {
    __shared__ __align__(16) unsigned char sA[16384];   // swizzled 128 n x 64 e bf16
    __shared__ __align__(16) unsigned char sB[4096];    // swizzled 32 g x 64 e bf16
    __shared__ __align__(16) uint4 slut[256];
    int t = threadIdx.x;
    slut[t] = lut_entry(t);

    int mt = blockIdx.x >> 2, qg = blockIdx.x & 3;
    int n0 = mt * 128, g0 = qg * 32;

    float4v acc[4];
#pragma unroll
    for (int i = 0; i < 4; ++i)
#pragma unroll
        for (int r = 0; r < 4; ++r) acc[i][r] = 0.0f;

    int wave = t >> 6, lane = t & 63;
    int wm0 = (wave & 1) * 64, wc0 = (wave >> 1) * 16;
    int r0 = lane & 15, q = lane >> 4;

    const unsigned* arow = packed + (size_t)(n0 + (t & 127)) * NW_E;
    const unsigned short* bbase = Ut + (size_t)qg * 2048;
    int t2 = t - 128;
    uint4 aw, aw2;
    if (t < 128) aw = *reinterpret_cast<const uint4*>(arow);
    __syncthreads();   // LUT ready

    for (int it = 0; it < 64; ++it) {
        if (t < 128) {
            unsigned w0, w1;
            if (!(it & 1)) {
                aw2 = *reinterpret_cast<const uint4*>(arow + 2 * it + 4);  // over-read benign
                w0 = aw.x; w1 = aw.y;
            } else {
                w0 = aw.z; w1 = aw.w;
            }
            int rA = t;
#pragma unroll
            for (int c = 0; c < 4; ++c)
                *reinterpret_cast<uint4*>(sA + lds_off(rA, c)) = slut[(w0 >> (c * 8)) & 0xFF];
#pragma unroll
            for (int c = 0; c < 4; ++c)
                *reinterpret_cast<uint4*>(sA + lds_off(rA, 4 + c)) = slut[(w1 >> (c * 8)) & 0xFF];
            if (it & 1) aw = aw2;
        } else {
            // B: 4KB contiguous (32 g-rows x 64 e), 128 thr x 2 x 16B
            const uint4* src = reinterpret_cast<const uint4*>(bbase + (size_t)it * 8192);
#pragma unroll
            for (int c = 0; c < 2; ++c) {
                int idx = t2 * 2 + c;
                uint4 v = src[idx];
                *reinterpret_cast<uint4*>(sB + lds_off(idx >> 3, idx & 7)) = v;
            }
        }
        __syncthreads();
#pragma unroll
        for (int ks = 0; ks < 2; ++ks) {
            short8v a[4], bb;
#pragma unroll
            for (int mi = 0; mi < 4; ++mi)
                a[mi] = *reinterpret_cast<const short8v*>(sA + lds_off(wm0 + mi * 16 + r0, ks * 4 + q));
            bb = *reinterpret_cast<const short8v*>(sB + lds_off(wc0 + r0, ks * 4 + q));
#pragma unroll
            for (int mi = 0; mi < 4; ++mi)
                acc[mi] = __builtin_amdgcn_mfma_f32_16x16x32_bf16(a[mi], bb, acc[mi], 0, 0, 0);
        }
        __syncthreads();
    }
    {
        int g = g0 + wc0 + r0;
        float bg = bias[g];
#pragma unroll
        for (int mi = 0; mi < 4; ++mi) {
#pragma unroll
            for (int r = 0; r < 4; ++r) {
                int n = n0 + wm0 + mi * 16 + q * 4 + r;
                if (n < NV) out[(size_t)n * 128 + g] = dv[n] * acc[mi][r] + bg;
            }
        }
    }
}

extern "C" void kernel_launch(void* const* d_in, const int* in_sizes, int n_in,
                              void* d_out, int out_size, void* d_ws, size_t ws_size,
                              hipStream_t stream) {
    const float* X    = (const float*)d_in[0];
    const int*   H    = (const int*)d_in[1];
    const float* W    = (const float*)d_in[2];
    const float* bias = (const float*)d_in[3];
    float* out = (float*)d_out;

    char* ws = (char*)d_ws;
    size_t off = 0;
    auto alloc = [&](size_t sz) { char* p = ws + off; off += (sz + 255) & ~(size_t)255; return p; };
    unsigned*       packed  = (unsigned*)alloc((size_t)NV * NW_E * 4);          // 10.24 MB
    unsigned*       packedT = (unsigned*)alloc((size_t)NE * PT_STRIDE * 4);     // 10.35 MB
    unsigned short* At      = (unsigned short*)alloc((size_t)NKC * 8192 * 2);   //  5.13 MB
    unsigned short* Ut      = (unsigned short*)alloc((size_t)FT * NE * 2);      //  1.05 MB
    float*          dv      = (float*)alloc((size_t)NV * 4);
    int*            edeg    = (int*)alloc((size_t)NE * 4);
    size_t fixed = off;

    long long avail = (long long)ws_size - (long long)fixed;
    int S = (int)(avail / (128LL * 4096 * 4));
    if (S > 16) S = 16;
    if (S < 1) S = 1;
    float* P1 = (float*)(ws + fixed);
    int chunkK = ((NKC * 64 + S * 64 - 1) / (S * 64)) * 64;

    hipMemsetAsync(edeg, 0, (size_t)NE * 4, stream);
    k_pack <<<NV / 2, 256, 0, stream>>>(H, packed, dv);
    k_prep <<<11267, 256, 0, stream>>>(packed, X, dv, packedT, edeg, At);
    k_mm1  <<<32 * S, 256, 0, stream>>>(At, packedT, P1, chunkK);
    k_ut2  <<<128, 256, 0, stream>>>(P1, W, edeg, Ut, S);
    k_mm2  <<<628, 256, 0, stream>>>(packed, Ut, dv, bias, out);
}

// Round 12
// 604.117 us; speedup vs baseline: 1.1482x; 1.1027x over previous
//
#include <hip/hip_runtime.h>

#define NV 20000          // vertices
#define NE 4096           // hyperedges
#define FT 128            // features
#define NW_E 128          // u32 words per packed vertex row  (E/32)
#define NW_V 625          // real u32 words per packedT edge row (N/32)
#define PT_STRIDE 632     // padded packedT row stride (prefetch may read past word 625)
#define NKC 313           // padded n-chunks of 64 (313*64 = 20032)

typedef __attribute__((ext_vector_type(8))) short short8v;   // 8 bf16 — MFMA A/B frag
typedef __attribute__((ext_vector_type(4))) float float4v;   // 4 fp32 — MFMA C/D frag

__device__ __forceinline__ unsigned short f2bf(float f) {    // fp32 -> bf16 RNE
    unsigned u = __float_as_uint(f);
    u += 0x7FFFu + ((u >> 16) & 1u);
    return (unsigned short)(u >> 16);
}
// swizzled LDS tile: rows of 64 bf16 (128B), 16B chunks XORed by row
__device__ __forceinline__ int lds_off(int r, int chunk) {
    return r * 128 + ((chunk ^ (r & 7)) << 4);
}
// 16B LUT entry: byte -> 8 bf16 in {0.0, 1.0}
__device__ __forceinline__ uint4 lut_entry(int t) {
    uint4 e;
    e.x = ((t & 1) ? 0x3F80u : 0u) | ((t & 2) ? 0x3F800000u : 0u);
    e.y = ((t & 4) ? 0x3F80u : 0u) | ((t & 8) ? 0x3F800000u : 0u);
    e.z = ((t & 16) ? 0x3F80u : 0u) | ((t & 32) ? 0x3F800000u : 0u);
    e.w = ((t & 64) ? 0x3F80u : 0u) | ((t & 128) ? 0x3F800000u : 0u);
    return e;
}

// ---------------- 1. pack H -> bits, coalesced: wave = half row ----------------
__global__ __launch_bounds__(256) void k_pack(const int* __restrict__ H,
                                              unsigned* __restrict__ packed,
                                              float* __restrict__ dv) {
    __shared__ int cl[4];
    int t = threadIdx.x, wave = t >> 6, lane = t & 63;
    int row = blockIdx.x * 2 + (wave >> 1);
    int half = wave & 1;
    const uint4* base = reinterpret_cast<const uint4*>(H) + (size_t)row * 1024 + half * 512 + lane * 8;
    unsigned m = 0;
#pragma unroll
    for (int i = 0; i < 8; ++i) {
        uint4 v = base[i];
        m |= (v.x ? 1u : 0u) << (i * 4 + 0);
        m |= (v.y ? 1u : 0u) << (i * 4 + 1);
        m |= (v.z ? 1u : 0u) << (i * 4 + 2);
        m |= (v.w ? 1u : 0u) << (i * 4 + 3);
    }
    packed[(size_t)row * NW_E + half * 64 + lane] = m;
    int c = __popc(m);
    for (int o = 32; o > 0; o >>= 1) c += __shfl_down(c, o, 64);
    if (lane == 0) cl[wave] = c;
    __syncthreads();
    if (t < 2) {
        int d = cl[t * 2] + cl[t * 2 + 1];
        dv[blockIdx.x * 2 + t] = d > 0 ? 1.0f / sqrtf((float)d) : 1.0f;
    }
}

// ---------------- 2. bit-transpose packed -> packedT via ballot ----------------
__global__ __launch_bounds__(256) void k_btrans(const unsigned* __restrict__ packed,
                                                unsigned* __restrict__ packedT) {
    int lane = threadIdx.x & 63;
    int w = threadIdx.x >> 6;
    int ew = blockIdx.y * 4 + w;
    int n = blockIdx.x * 64 + lane;
    unsigned wv = (n < NV) ? packed[(size_t)n * NW_E + ew] : 0u;
    unsigned my = 0;
#pragma unroll
    for (int j = 0; j < 32; ++j) {
        unsigned long long m = __ballot(((wv >> j) & 1u) != 0);
        unsigned part = (lane < 32) ? (unsigned)m : (unsigned)(m >> 32);
        if ((lane & 31) == j) my = part;
    }
    int nw = blockIdx.x * 2 + (lane >> 5);
    int e = ew * 32 + (lane & 31);
    if (nw <= 625) packedT[(size_t)e * PT_STRIDE + nw] = my;
}

// ---------------- 3. edge degree | At tiled build ----------------
// blocks [0,1024): edge degree from packedT popcounts. [1024,2274): At[kc][f][64n]=bf16(dv*X).
// block 2274: zero-pad chunk kc=312 tail.
__global__ __launch_bounds__(256) void k_mid(const unsigned* __restrict__ packedT,
                                             const float* __restrict__ X,
                                             const float* __restrict__ dv,
                                             float* __restrict__ de,
                                             unsigned short* __restrict__ At) {
    int b = blockIdx.x, t = threadIdx.x;
    int wave = t >> 6, lane = t & 63;
    if (b < 1024) {
        int e = b * 4 + wave;
        const unsigned* row = packedT + (size_t)e * PT_STRIDE;
        int c = 0;
        for (int i = lane; i < NW_V; i += 64) c += __popc(row[i]);
        for (int o = 32; o > 0; o >>= 1) c += __shfl_down(c, o, 64);
        if (lane == 0) de[e] = c > 0 ? 1.0f / (float)c : 1.0f;
    } else if (b < 2274) {
        int b2 = b - 1024;
        int f = t & 127;
        int nb = (b2 * 2 + (t >> 7)) * 8;   // 1250 virt * 16 n == 20000 exactly
        unsigned short h[8];
#pragma unroll
        for (int i = 0; i < 8; ++i) {
            int n = nb + i;
            h[i] = f2bf(X[(size_t)n * FT + f] * dv[n]);
        }
        uint4 u;
        u.x = (unsigned)h[0] | ((unsigned)h[1] << 16);
        u.y = (unsigned)h[2] | ((unsigned)h[3] << 16);
        u.z = (unsigned)h[4] | ((unsigned)h[5] << 16);
        u.w = (unsigned)h[6] | ((unsigned)h[7] << 16);
        int kc = nb >> 6;
        *reinterpret_cast<uint4*>(At + (size_t)kc * 8192 + f * 64 + (nb & 63)) = u;
    } else {
        // zero pad chunk kc=312, j in [32,64)
        int f = t & 127;
        uint4 z = {0, 0, 0, 0};
        *reinterpret_cast<uint4*>(At + (size_t)312 * 8192 + f * 64 + 32 + (t >> 7) * 8) = z;
        *reinterpret_cast<uint4*>(At + (size_t)312 * 8192 + f * 64 + 48 + (t >> 7) * 8) = z;
    }
}

// ---------------- 4. mm1: P[kp][f][e] = sum_n At[f][n] * H[n][e], split-K ----------------
// R5-exact: A staged bf16 coalesced; B bits -> LUT expansion at staging time.
__global__ __launch_bounds__(256, 2) void k_mm1(const unsigned short* __restrict__ At,
                                                const unsigned* __restrict__ packedT,
                                                float* __restrict__ P, int chunkK) {
    __shared__ __align__(16) unsigned char sA[16384];   // swizzled 128 f x 64 n bf16
    __shared__ __align__(16) unsigned char sB[16384];   // swizzled 128 e x 64 n bf16
    __shared__ __align__(16) uint4 slut[256];
    int t = threadIdx.x;
    slut[t] = lut_entry(t);

    int et = blockIdx.x & 31, kp = blockIdx.x >> 5;
    int e0 = et * 128;
    int kbeg = kp * chunkK;
    int kend = kbeg + chunkK; if (kend > NKC * 64) kend = NKC * 64;
    int iters = (kend - kbeg) >> 6; if (iters < 0) iters = 0;

    float4v acc[4][4];
#pragma unroll
    for (int i = 0; i < 4; ++i)
#pragma unroll
        for (int j = 0; j < 4; ++j)
#pragma unroll
            for (int r = 0; r < 4; ++r) acc[i][j][r] = 0.0f;

    int wave = t >> 6, lane = t & 63;
    int wm0 = (wave & 1) * 64, wc0 = (wave >> 1) * 64;
    int r0 = lane & 15, q = lane >> 4;

    // B prefetch: thread t<128 owns e-row t; uint4 = 4 words = 2 iters
    const unsigned* brow = packedT + (size_t)(e0 + (t & 127)) * PT_STRIDE + (kbeg >> 5);
    uint4 bw, bw2;
    if (t < 128) bw = *reinterpret_cast<const uint4*>(brow);
    __syncthreads();   // LUT ready

    for (int it = 0; it < iters; ++it) {
        int kc = (kbeg >> 6) + it;
        // stage A: 16KB contiguous slab, 256 thr x 4 x 16B, per-instr coalesced
        const uint4* slab = reinterpret_cast<const uint4*>(At + (size_t)kc * 8192);
#pragma unroll
        for (int c = 0; c < 4; ++c) {
            int idx = c * 256 + t;
            uint4 v = slab[idx];
            *reinterpret_cast<uint4*>(sA + lds_off(idx >> 3, idx & 7)) = v;
        }
        // stage B: 2 words/row via LUT; prefetch next pair at even iters
        if (t < 128) {
            unsigned w0, w1;
            if (!(it & 1)) {
                bw2 = *reinterpret_cast<const uint4*>(brow + 2 * it + 4);  // pad keeps in-bounds
                w0 = bw.x; w1 = bw.y;
            } else {
                w0 = bw.z; w1 = bw.w;
            }
            int rB = t;
#pragma unroll
            for (int c = 0; c < 4; ++c)
                *reinterpret_cast<uint4*>(sB + lds_off(rB, c)) = slut[(w0 >> (c * 8)) & 0xFF];
#pragma unroll
            for (int c = 0; c < 4; ++c)
                *reinterpret_cast<uint4*>(sB + lds_off(rB, 4 + c)) = slut[(w1 >> (c * 8)) & 0xFF];
            if (it & 1) bw = bw2;
        }
        __syncthreads();
#pragma unroll
        for (int ks = 0; ks < 2; ++ks) {
            short8v a[4], bb[4];
#pragma unroll
            for (int mi = 0; mi < 4; ++mi)
                a[mi] = *reinterpret_cast<const short8v*>(sA + lds_off(wm0 + mi * 16 + r0, ks * 4 + q));
#pragma unroll
            for (int ci = 0; ci < 4; ++ci)
                bb[ci] = *reinterpret_cast<const short8v*>(sB + lds_off(wc0 + ci * 16 + r0, ks * 4 + q));
#pragma unroll
            for (int mi = 0; mi < 4; ++mi)
#pragma unroll
                for (int ci = 0; ci < 4; ++ci)
                    acc[mi][ci] = __builtin_amdgcn_mfma_f32_16x16x32_bf16(a[mi], bb[ci], acc[mi][ci], 0, 0, 0);
        }
        __syncthreads();
    }
    float* Pp = P + (size_t)kp * (128 * 4096);
#pragma unroll
    for (int mi = 0; mi < 4; ++mi)
#pragma unroll
        for (int ci = 0; ci < 4; ++ci) {
            int f = wm0 + mi * 16 + q * 4;
            int e = e0 + wc0 + ci * 16 + r0;
#pragma unroll
            for (int r = 0; r < 4; ++r)
                Pp[(size_t)(f + r) * 4096 + e] = acc[mi][ci][r];
        }
}

// ---------------- 5. fused reduce + Ut: Ut[ec][g][64e] = bf16( de * (sum_p P)^T W ) ----------------
// 128 blocks x 32 e. Phase A: sum S partials into 16KB LDS tile. Phase B: fp32 epilogue GEMM.
__global__ __launch_bounds__(256) void k_ut2(const float* __restrict__ P,
                                             const float* __restrict__ W,
                                             const float* __restrict__ de,
                                             unsigned short* __restrict__ Ut, int S) {
    __shared__ float sT[128][32];   // 16 KB, [f][e-local]
    int t = threadIdx.x;
    int e0 = blockIdx.x * 32;
    int el = t & 31;
    int fb = t >> 5;                // 0..7
    float a[16];
#pragma unroll
    for (int i = 0; i < 16; ++i) a[i] = 0.0f;
    for (int p = 0; p < S; ++p) {
        const float* Pp = P + (size_t)p * 524288 + e0 + el;
#pragma unroll
        for (int i = 0; i < 16; ++i)
            a[i] += Pp[(size_t)(fb + i * 8) * 4096];
    }
#pragma unroll
    for (int i = 0; i < 16; ++i) sT[fb + i * 8][el] = a[i];
    __syncthreads();
    // phase B: thread = (el, gq = t>>5): 16 g outputs
    int g0 = (t >> 5) * 16;
    float acc[16];
#pragma unroll
    for (int j = 0; j < 16; ++j) acc[j] = 0.0f;
    for (int f = 0; f < 128; ++f) {
        float tv = sT[f][el];
#pragma unroll
        for (int j = 0; j < 4; ++j) {
            float4 wv = *reinterpret_cast<const float4*>(W + f * 128 + g0 + j * 4);
            acc[j * 4 + 0] += tv * wv.x;
            acc[j * 4 + 1] += tv * wv.y;
            acc[j * 4 + 2] += tv * wv.z;
            acc[j * 4 + 3] += tv * wv.w;
        }
    }
    int e = e0 + el;
    float d = de[e];
    size_t base = (size_t)(e >> 6) * 8192 + (e & 63);
#pragma unroll
    for (int j = 0; j < 16; ++j)
        Ut[base + (size_t)(g0 + j) * 64] = f2bf(acc[j] * d);
}

// ---------------- 6. mm2: out[n][g] = dv[n]*sum_e H[n][e]*U[g][e] + bias[g] ----------------
// R5-exact: A bits -> LUT at staging (t<128, uint4 prefetch); B bf16 from tiled Ut (t>=128).
__global__ __launch_bounds__(256, 4) void k_mm2(const unsigned* __restrict__ packed,
                                                const unsigned short* __restrict__ Ut,
                                                const float* __restrict__ dv,
                                                const float* __restrict__ bias,
                                                float* __restrict__ out) {
    __shared__ __align__(16) unsigned char sA[16384];   // swizzled 128 n x 64 e bf16
    __shared__ __align__(16) unsigned char sB[4096];    // swizzled 32 g x 64 e bf16
    __shared__ __align__(16) uint4 slut[256];
    int t = threadIdx.x;
    slut[t] = lut_entry(t);

    int mt = blockIdx.x >> 2, qg = blockIdx.x & 3;
    int n0 = mt * 128, g0 = qg * 32;

    float4v acc[4];
#pragma unroll
    for (int i = 0; i < 4; ++i)
#pragma unroll
        for (int r = 0; r < 4; ++r) acc[i][r] = 0.0f;

    int wave = t >> 6, lane = t & 63;
    int wm0 = (wave & 1) * 64, wc0 = (wave >> 1) * 16;
    int r0 = lane & 15, q = lane >> 4;

    const unsigned* arow = packed + (size_t)(n0 + (t & 127)) * NW_E;
    const unsigned short* bbase = Ut + (size_t)qg * 2048;
    int t2 = t - 128;
    uint4 aw, aw2;
    if (t < 128) aw = *reinterpret_cast<const uint4*>(arow);
    __syncthreads();   // LUT ready

    for (int it = 0; it < 64; ++it) {
        if (t < 128) {
            unsigned w0, w1;
            if (!(it & 1)) {
                aw2 = *reinterpret_cast<const uint4*>(arow + 2 * it + 4);  // over-read benign
                w0 = aw.x; w1 = aw.y;
            } else {
                w0 = aw.z; w1 = aw.w;
            }
            int rA = t;
#pragma unroll
            for (int c = 0; c < 4; ++c)
                *reinterpret_cast<uint4*>(sA + lds_off(rA, c)) = slut[(w0 >> (c * 8)) & 0xFF];
#pragma unroll
            for (int c = 0; c < 4; ++c)
                *reinterpret_cast<uint4*>(sA + lds_off(rA, 4 + c)) = slut[(w1 >> (c * 8)) & 0xFF];
            if (it & 1) aw = aw2;
        } else {
            // B: 4KB contiguous (32 g-rows x 64 e), 128 thr x 2 x 16B
            const uint4* src = reinterpret_cast<const uint4*>(bbase + (size_t)it * 8192);
#pragma unroll
            for (int c = 0; c < 2; ++c) {
                int idx = t2 * 2 + c;
                uint4 v = src[idx];
                *reinterpret_cast<uint4*>(sB + lds_off(idx >> 3, idx & 7)) = v;
            }
        }
        __syncthreads();
#pragma unroll
        for (int ks = 0; ks < 2; ++ks) {
            short8v a[4], bb;
#pragma unroll
            for (int mi = 0; mi < 4; ++mi)
                a[mi] = *reinterpret_cast<const short8v*>(sA + lds_off(wm0 + mi * 16 + r0, ks * 4 + q));
            bb = *reinterpret_cast<const short8v*>(sB + lds_off(wc0 + r0, ks * 4 + q));
#pragma unroll
            for (int mi = 0; mi < 4; ++mi)
                acc[mi] = __builtin_amdgcn_mfma_f32_16x16x32_bf16(a[mi], bb, acc[mi], 0, 0, 0);
        }
        __syncthreads();
    }
    {
        int g = g0 + wc0 + r0;
        float bg = bias[g];
#pragma unroll
        for (int mi = 0; mi < 4; ++mi) {
#pragma unroll
            for (int r = 0; r < 4; ++r) {
                int n = n0 + wm0 + mi * 16 + q * 4 + r;
                if (n < NV) out[(size_t)n * 128 + g] = dv[n] * acc[mi][r] + bg;
            }
        }
    }
}

extern "C" void kernel_launch(void* const* d_in, const int* in_sizes, int n_in,
                              void* d_out, int out_size, void* d_ws, size_t ws_size,
                              hipStream_t stream) {
    const float* X    = (const float*)d_in[0];
    const int*   H    = (const int*)d_in[1];
    const float* W    = (const float*)d_in[2];
    const float* bias = (const float*)d_in[3];
    float* out = (float*)d_out;

    char* ws = (char*)d_ws;
    size_t off = 0;
    auto alloc = [&](size_t sz) { char* p = ws + off; off += (sz + 255) & ~(size_t)255; return p; };
    unsigned*       packed  = (unsigned*)alloc((size_t)NV * NW_E * 4);          // 10.24 MB
    unsigned*       packedT = (unsigned*)alloc((size_t)NE * PT_STRIDE * 4);     // 10.35 MB
    unsigned short* At      = (unsigned short*)alloc((size_t)NKC * 8192 * 2);   //  5.13 MB
    unsigned short* Ut      = (unsigned short*)alloc((size_t)FT * NE * 2);      //  1.05 MB
    float*          dv      = (float*)alloc((size_t)NV * 4);
    float*          de      = (float*)alloc((size_t)NE * 4);
    size_t fixed = off;

    long long avail = (long long)ws_size - (long long)fixed;
    int S = (int)(avail / (128LL * 4096 * 4));
    if (S > 16) S = 16;
    if (S < 1) S = 1;
    float* P1 = (float*)(ws + fixed);
    int chunkK = ((NKC * 64 + S * 64 - 1) / (S * 64)) * 64;

    k_pack  <<<NV / 2, 256, 0, stream>>>(H, packed, dv);
    k_btrans<<<dim3(313, 32), 256, 0, stream>>>(packed, packedT);
    k_mid   <<<2275, 256, 0, stream>>>(packedT, X, dv, de, At);
    k_mm1   <<<32 * S, 256, 0, stream>>>(At, packedT, P1, chunkK);
    k_ut2   <<<128, 256, 0, stream>>>(P1, W, de, Ut, S);
    k_mm2   <<<628, 256, 0, stream>>>(packed, Ut, dv, bias, out);
}